// Round 10
// baseline (147.615 us; speedup 1.0000x reference)
//
#include <hip/hip_runtime.h>

// Conv2D 3x3 stride-1 pad-1, C_IN=C_OUT=16, H=W=1024, fp32 in/out.
// Fused implicit-GEMM. v10: 12 independent desynchronized wave-streams/CU.
//  - r9 killed the convoy theory (33% occupancy, fine phases, still 56us):
//    reads are latency*outstanding limited, and BARRIERS convoy all waves
//    into shared read-silent windows regardless of wave count. v8 (no
//    barriers) had continuous demand but only 4 streams/CU.
//  - v10 = v8's passing independent-wave structure, 3x the streams:
//    wave = 64x4 output tile, exactly 6 input rows -> flat 6-slot LDS
//    buffer (no ring arithmetic). 4 independent waves per 256-thr block,
//    12672 B LDS each = 50688 B/block -> 3 blocks/CU = 12 waves/CU; grid
//    16x64 = 1024 blocks, rolling replacement desynchronizes streams.
//  - ZERO barriers, zero waitcnt asm. Ordering: per-wave in-order DS pipe
//    + compiler-counted vmcnt (v8-validated). Every body pack waits its
//    loads with NEWER loads outstanding -> counted wait, never drains the
//    output stores (the r0-r3 poison).
//  - halo cols (-1, 64) live in a separate 384B strip per wave, filled in
//    the prologue (no stores outstanding -> its vmcnt(0) is harmless).
//    Body staging is then perfectly uniform: 2 px-tasks/lane, 16
//    channel-strided scalar loads each (64 lanes x 4B = 256B dense), no
//    tail lanes, no gw guards.
//  - compute: per row 4 colgroups x 5 mfma_f32_16x16x32_bf16; halo lanes
//    (col -1/64) select the strip address via cndmask.
//  - per-wave pipeline: L0 L1 [halo] W0 L2 W1 C0 W2 C1 - loads in flight
//    in every phase except the last compute; 12 staggered waves/CU cover
//    each other's tails.

#define HH 1024
#define WW 1024
#define CIN 16
#define HWP (HH * WW)
#define TW 64
#define RPW 4                  // output rows per wave
#define WPB 4                  // waves per block
#define HCB 768                // halo chunk base (6 slots * 64 px * 2)
#define WLDS 6336              // shorts per wave: (768+24)*8 = 12672 B

typedef short v8s __attribute__((ext_vector_type(8)));
typedef float v4f __attribute__((ext_vector_type(4)));
typedef unsigned int u32;

// packed {bf16(hi)<<16 | bf16(lo)}, hardware RNE
__device__ __forceinline__ u32 cvt_pk_bf16(float lo, float hi) {
    u32 r;
    asm("v_cvt_pk_bf16_f32 %0, %1, %2" : "=v"(r) : "v"(lo), "v"(hi));
    return r;
}

__device__ __forceinline__ int swz(int c) { return c ^ ((c >> 3) & 7); }

__global__ __launch_bounds__(256, 3)
void conv3x3_iw(const float* __restrict__ x,
                const float* __restrict__ wgt,
                const float* __restrict__ bias,
                float* __restrict__ out) {
    __shared__ __align__(16) unsigned short sm[WPB * WLDS];   // 50688 B

    const int tid = threadIdx.x;
    const int lane = tid & 63;
    const int wave = tid >> 6;
    const int m = lane & 15;       // c_out row of A == pixel col of B/D
    const int q = lane >> 4;       // k-quad: supplies k = 8q..8q+7
    const int w0 = blockIdx.x * TW;
    const int y0 = (blockIdx.y * WPB + wave) * RPW;
    unsigned short* smw = sm + wave * WLDS;

    // ---- weight fragments in registers (gather from hot 9KB, L2-res) ----
    // a[g5] elem j = W[m][(t&1)*8+j][kh][kw], t = 4*g5+q, kh*3+kw = t>>1.
    v8s a[5];
    #pragma unroll
    for (int g5 = 0; g5 < 5; ++g5) {
        const int t = 4 * g5 + q;
        union { u32 u[4]; v8s v; } wv;
        if (t < 18) {
            const int base = m * 144 + (t & 1) * 72 + (t >> 1);
            #pragma unroll
            for (int jj = 0; jj < 4; ++jj) {
                const float lo = wgt[base + 18 * jj];      // j = 2jj
                const float hi = wgt[base + 18 * jj + 9];  // j = 2jj+1
                wv.u[jj] = cvt_pk_bf16(lo, hi);
            }
        } else {
            wv.u[0] = wv.u[1] = wv.u[2] = wv.u[3] = 0u;
        }
        a[g5] = wv.v;
    }
    float bl[4];
    #pragma unroll
    for (int i = 0; i < 4; ++i) bl[i] = bias[q * 4 + i];

    // ---- per-lane tap decomposition: t = 4g+q -> kh, m+kw, chunk half ----
    int mkw[5], hf5[5], kh5[5];
    #pragma unroll
    for (int g5 = 0; g5 < 5; ++g5) {
        int t = 4 * g5 + q;
        int tt = t > 17 ? 17 : t;      // dead lanes use a harmless valid addr
        int khkw = tt >> 1;
        int kh = khkw / 3;
        int kw = khkw - 3 * kh;
        kh5[g5] = kh;
        mkw[g5] = m + kw;
        hf5[g5] = tt & 1;
    }

    // ---- body staging: step s covers input slots 2s, 2s+1 (rows y0-1+slot);
    //      lane = body col (gw = w0+lane, always in range); 16 scalar loads
    //      per row = 256B-dense per instruction ----
    auto loadS = [&](int s, float* f) {     // f[32] = [z*16 + ch]
        #pragma unroll
        for (int z = 0; z < 2; ++z) {
            const int gh = y0 - 1 + 2 * s + z;
            if ((unsigned)gh < (unsigned)HH) {
                const float* p = x + (size_t)gh * WW + (w0 + lane);
                #pragma unroll
                for (int c = 0; c < CIN; ++c)
                    f[z * 16 + c] = p[(size_t)c * HWP];
            } else {
                #pragma unroll
                for (int c = 0; c < CIN; ++c)
                    f[z * 16 + c] = 0.f;
            }
        }
    };
    auto writeS = [&](int s, const float* f) {
        #pragma unroll
        for (int z = 0; z < 2; ++z) {
            const int slot = 2 * s + z;                 // static 0..5
            u32 pk[8];
            #pragma unroll
            for (int i = 0; i < 8; ++i)
                pk[i] = cvt_pk_bf16(f[z * 16 + 2 * i], f[z * 16 + 2 * i + 1]);
            const int c0 = slot * 128 + lane * 2;
            *(uint4*)(smw + swz(c0) * 8)     = *(uint4*)&pk[0];
            *(uint4*)(smw + swz(c0 + 1) * 8) = *(uint4*)&pk[4];
        }
    };

    // ---- halo strip: 12 px (6 slots x {colL,colR}) x 8 ch-pairs = 96 tasks
    //      task p = lane + 64j (j=0,1): hp = p>>3 (slot*2+side), pc = p&7.
    //      Strip layout: chunk HCB + slot*4 + side*2 + half, NOT swizzled. ----
    float2 hA, hB;
    auto haloLoad = [&](int j, float2& fp) {
        const int p = lane + 64 * j;
        if (p < 96) {
            const int hp = p >> 3, pc = p & 7;
            const int slot = hp >> 1, side = hp & 1;
            const int gh = y0 - 1 + slot;
            const int gw = side ? (w0 + TW) : (w0 - 1);
            if ((unsigned)gh < (unsigned)HH && (unsigned)gw < (unsigned)WW) {
                const float* p2 = x + (size_t)gh * WW + gw;
                fp.x = p2[(size_t)(2 * pc) * HWP];
                fp.y = p2[(size_t)(2 * pc + 1) * HWP];
            } else {
                fp.x = 0.f; fp.y = 0.f;
            }
        }
    };
    auto haloWrite = [&](int j, float2 fp) {
        const int p = lane + 64 * j;
        if (p < 96) {
            const int hp = p >> 3, pc = p & 7;
            const u32 pk = cvt_pk_bf16(fp.x, fp.y);
            const int ch = HCB + hp * 2 + (pc >> 2);    // chunk index
            *(u32*)(smw + ch * 8 + (pc & 3) * 2) = pk;
        }
    };

    // ---- compute pair k: output rows y0+2k, y0+2k+1 ----
    auto computeP = [&](int k) {
        #pragma unroll
        for (int rr = 0; rr < 2; ++rr) {
            const int ib = 2 * k + rr;          // slot of row-1 (static)
            const int R = y0 + ib;
            #pragma unroll
            for (int g16 = 0; g16 < 4; ++g16) {
                v4f acc = {0.f, 0.f, 0.f, 0.f};
                #pragma unroll
                for (int g5 = 0; g5 < 5; ++g5) {
                    const int slot = ib + kh5[g5];            // 0..5 lane-dep
                    const int col = g16 * 16 + mkw[g5] - 1;   // -1..64
                    const int cb = swz(slot * 128 + (col & 63) * 2 + hf5[g5]);
                    const int chl = HCB + slot * 4 + ((col == 64) ? 2 : 0) + hf5[g5];
                    const int c = ((unsigned)col < 64u) ? cb : chl;
                    v8s b = *(const v8s*)(smw + c * 8);
                    acc = __builtin_amdgcn_mfma_f32_16x16x32_bf16(a[g5], b, acc, 0, 0, 0);
                }
                float* op = out + (size_t)R * WW + (w0 + g16 * 16 + m);
                #pragma unroll
                for (int i = 0; i < 4; ++i)
                    op[(size_t)(q * 4 + i) * HWP] = acc[i] + bl[i];
            }
        }
    };

    // ---- barrier-free per-wave pipeline ----
    float A[32], B[32];
    loadS(0, A);                   // issue slots 0,1
    loadS(1, B);                   // issue slots 2,3
    haloLoad(0, hA);
    haloLoad(1, hB);
    haloWrite(0, hA);              // waits halo (prologue: no stores yet)
    haloWrite(1, hB);
    writeS(0, A);                  // waits S0 loads (S1 stay outstanding)
    loadS(2, A);                   // issue slots 4,5 (A freed by writeS(0))
    writeS(1, B);                  // waits S1; S2 outstanding
    computeP(0);                   // rows y0,y0+1: slots 0..3; S2 in flight
    writeS(2, A);                  // waits S2; counted past C0's stores
    computeP(1);                   // rows y0+2,y0+3: slots 2..5
}

extern "C" void kernel_launch(void* const* d_in, const int* in_sizes, int n_in,
                              void* d_out, int out_size, void* d_ws, size_t ws_size,
                              hipStream_t stream) {
    const float* x = (const float*)d_in[0];
    const float* w = (const float*)d_in[1];
    const float* b = (const float*)d_in[2];
    float* out = (float*)d_out;
    dim3 grid(WW / TW, HH / (RPW * WPB));
    conv3x3_iw<<<grid, dim3(256), 0, stream>>>(x, w, b, out);
}

// Round 12
// 137.020 us; speedup vs baseline: 1.0773x; 1.0773x over previous
//
#include <hip/hip_runtime.h>

// Conv2D 3x3 stride-1 pad-1, C_IN=C_OUT=16, H=W=1024, fp32 in/out.
// Fused implicit-GEMM. v11: 1KB-contiguous global reads (DRAM-row theory).
// (Resubmission — round 11 failed on container acquisition, not the kernel;
//  identical source, paper re-audit passed.)
//  - Ten rounds of schedule variants (barriers coarse/fine, barrier-free,
//    1-32 streams/CU) ALL sit at 2.4-3.5 TB/s read BW. Schedule is not the
//    variable. The untouched axis: read granularity. Per (ch,row) we read
//    256B chunks, 16 channels 4MB apart; chip-wide that is ~20K distinct
//    DRAM rows in flight vs ~1K open-row capacity -> every 256B pays an
//    activation, ~25-40% row efficiency = the 2-3.5 TB/s band. Contiguous
//    proofs on this chip: fillBuffer 6.5 TB/s, float4 copy 6.3 TB/s.
//  - v11: TW=256 -> each wave-instruction reads 64 lanes x 16B = 1KB
//    contiguous per (ch,row). TH=4. Single-shot block: stage 6 input rows,
//    ONE raw barrier, compute 4 output rows. Clean A/B vs r0 (same 3
//    blocks/CU, same coarse phasing; only contiguity changed).
//  - LDS: 6 slots x 258 px x 32B = 49536B -> 3 blocks/CU; grid 1024 blocks
//    (rolling replacement desyncs). Launched y-fastest: vertically adjacent
//    blocks (sharing 2 halo rows) are dispatch-adjacent -> co-XCD -> L2
//    absorbs the 6/4 vertical amp.
//  - Staging: 3 sweeps of 2 slots; thread = (slot, ch-half, 4px group):
//    8x float4 loads (1KB/instr contiguity), 4 cvt_pk per px, 4 swizzled
//    ds_write_b128. VGPR ~110 (<=128 for 3/SIMD). Halo: 12 px x 16 ch on
//    tid<12, same chunk layout (swizzled) as body.
//  - Barrier: lgkm-only + s_barrier (r5-validated). Zero stores outstanding
//    at the barrier -> no store-drain anywhere.
//  - Compute: wave w owns cols w*64..w*64+63: 4 rows x 4 colgroups x
//    5 mfma_f32_16x16x32_bf16; weights via validated register gather.

#define HH 1024
#define WW 1024
#define CIN 16
#define HWP (HH * WW)
#define TW 256
#define TH 4
#define SLOTS 6
#define PPS 258                // px per slot (cols -1..256)
#define CPS (PPS * 2)          // chunks per slot = 516

typedef short v8s __attribute__((ext_vector_type(8)));
typedef float v4f __attribute__((ext_vector_type(4)));
typedef unsigned int u32;

// packed {bf16(hi)<<16 | bf16(lo)}, hardware RNE
__device__ __forceinline__ u32 cvt_pk_bf16(float lo, float hi) {
    u32 r;
    asm("v_cvt_pk_bf16_f32 %0, %1, %2" : "=v"(r) : "v"(lo), "v"(hi));
    return r;
}

__device__ __forceinline__ int swz(int c) { return c ^ ((c >> 3) & 7); }

// Workgroup barrier WITHOUT the vmcnt(0) store/load drain __syncthreads adds.
__device__ __forceinline__ void wave_barrier() {
    __builtin_amdgcn_sched_barrier(0);
    asm volatile("s_waitcnt lgkmcnt(0)" ::: "memory");
    __builtin_amdgcn_sched_barrier(0);
    __builtin_amdgcn_s_barrier();
    __builtin_amdgcn_sched_barrier(0);
}

__global__ __launch_bounds__(256, 3)
void conv3x3_wide(const float* __restrict__ x,
                  const float* __restrict__ wgt,
                  const float* __restrict__ bias,
                  float* __restrict__ out) {
    __shared__ __align__(16) unsigned short sm[SLOTS * CPS * 8];  // 49536 B

    const int tid = threadIdx.x;
    const int lane = tid & 63;
    const int wave = tid >> 6;
    const int m = lane & 15;       // c_out row of A == pixel col of B/D
    const int q = lane >> 4;       // k-quad: supplies k = 8q..8q+7
    const int y0 = blockIdx.x * TH;   // y fastest: vertical neighbors co-XCD
    const int w0 = blockIdx.y * TW;

    // ---- weight fragments in registers (gather from hot 9KB, L2-res) ----
    // a[g5] elem j = W[m][(t&1)*8+j][kh][kw], t = 4*g5+q, kh*3+kw = t>>1.
    v8s a[5];
    #pragma unroll
    for (int g5 = 0; g5 < 5; ++g5) {
        const int t = 4 * g5 + q;
        union { u32 u[4]; v8s v; } wv;
        if (t < 18) {
            const int base = m * 144 + (t & 1) * 72 + (t >> 1);
            #pragma unroll
            for (int jj = 0; jj < 4; ++jj) {
                const float lo = wgt[base + 18 * jj];      // j = 2jj
                const float hi = wgt[base + 18 * jj + 9];  // j = 2jj+1
                wv.u[jj] = cvt_pk_bf16(lo, hi);
            }
        } else {
            wv.u[0] = wv.u[1] = wv.u[2] = wv.u[3] = 0u;
        }
        a[g5] = wv.v;
    }
    float bl[4];
    #pragma unroll
    for (int i = 0; i < 4; ++i) bl[i] = bias[q * 4 + i];

    // ---- per-lane tap decomposition: t = 4g+q -> kh, m+kw, chunk half ----
    int mkw[5], hf5[5], kh5[5];
    #pragma unroll
    for (int g5 = 0; g5 < 5; ++g5) {
        int t = 4 * g5 + q;
        int tt = t > 17 ? 17 : t;      // dead lanes use a harmless valid addr
        int khkw = tt >> 1;
        int kh = khkw / 3;
        int kw = khkw - 3 * kh;
        kh5[g5] = kh;
        mkw[g5] = m + kw;
        hf5[g5] = tt & 1;
    }

    // ---- staging sweep over slots {s0, s0+1}: thread -> slot s0+(tid>>7),
    //      channel half chh=(tid>>6)&1 (ch 8*chh..8*chh+7), 4px grp j=lane.
    //      Per wave-instruction: 64 lanes x 16B = 1KB CONTIGUOUS. ----
    auto loadSw = [&](int s0, float4* f8) {
        const int s = s0 + (tid >> 7);
        const int gh = y0 - 1 + s;
        const int c0 = ((tid >> 6) & 1) * 8;
        if ((unsigned)gh < (unsigned)HH) {
            const float4* src = (const float4*)(x + (size_t)gh * WW + w0) + lane;
            #pragma unroll
            for (int cc = 0; cc < 8; ++cc)
                f8[cc] = src[(size_t)(c0 + cc) * (HWP / 4)];
        } else {
            #pragma unroll
            for (int cc = 0; cc < 8; ++cc)
                f8[cc] = make_float4(0.f, 0.f, 0.f, 0.f);
        }
    };
    auto writeSw = [&](int s0, const float4* f8) {
        const int s = s0 + (tid >> 7);
        const int chh = (tid >> 6) & 1;
        #pragma unroll
        for (int k = 0; k < 4; ++k) {
            u32 pk[4];
            #pragma unroll
            for (int i = 0; i < 4; ++i) {
                const float lo = ((const float*)&f8[2 * i])[k];
                const float hi = ((const float*)&f8[2 * i + 1])[k];
                pk[i] = cvt_pk_bf16(lo, hi);
            }
            const int p = 1 + 4 * lane + k;            // body px index
            const int c = s * CPS + p * 2 + chh;
            *(uint4*)(sm + swz(c) * 8) = *(uint4*)pk;
        }
    };

    // ---- halo: 12 px (6 slots x cols {-1, 256}) x 16 ch on tid<12 ----
    auto haloLoad = [&](float* f) {
        const int slot = tid >> 1;
        const int side = tid & 1;
        const int gh = y0 - 1 + slot;
        const int gw = side ? (w0 + TW) : (w0 - 1);
        if ((unsigned)gh < (unsigned)HH && (unsigned)gw < (unsigned)WW) {
            const float* p2 = x + (size_t)gh * WW + gw;
            #pragma unroll
            for (int c = 0; c < CIN; ++c) f[c] = p2[(size_t)c * HWP];
        } else {
            #pragma unroll
            for (int c = 0; c < CIN; ++c) f[c] = 0.f;
        }
    };
    auto haloWrite = [&](const float* f) {
        const int slot = tid >> 1;
        const int side = tid & 1;
        const int p = side ? (PPS - 1) : 0;
        u32 pk[8];
        #pragma unroll
        for (int i = 0; i < 8; ++i)
            pk[i] = cvt_pk_bf16(f[2 * i], f[2 * i + 1]);
        const int c = slot * CPS + p * 2;
        *(uint4*)(sm + swz(c) * 8)     = *(uint4*)&pk[0];
        *(uint4*)(sm + swz(c + 1) * 8) = *(uint4*)&pk[4];
    };

    // ---- stage: 3 sweeps x 2 slots, single reg set (serial packs) ----
    float fh[16];
    if (tid < 12) haloLoad(fh);
    {
        float4 f8[8];
        loadSw(0, f8);
        writeSw(0, f8);
        loadSw(2, f8);
        writeSw(2, f8);
        loadSw(4, f8);
        writeSw(4, f8);
    }
    if (tid < 12) haloWrite(fh);

    wave_barrier();            // zero stores outstanding here: no drain cost

    // ---- compute: wave w owns cols w*64..w*64+63; rows y0..y0+3 ----
    const int wco = wave * 128;            // chunk offset of wave's col span
    #pragma unroll
    for (int r = 0; r < TH; ++r) {
        #pragma unroll
        for (int g16 = 0; g16 < 4; ++g16) {
            v4f acc = {0.f, 0.f, 0.f, 0.f};
            #pragma unroll
            for (int g5 = 0; g5 < 5; ++g5) {
                const int slot = r + kh5[g5];                  // 0..5
                const int c = slot * CPS + wco + g16 * 32 + mkw[g5] * 2 + hf5[g5];
                v8s b = *(const v8s*)(sm + swz(c) * 8);
                acc = __builtin_amdgcn_mfma_f32_16x16x32_bf16(a[g5], b, acc, 0, 0, 0);
            }
            float* op = out + (size_t)(y0 + r) * WW + (w0 + wave * 64 + g16 * 16 + m);
            #pragma unroll
            for (int i = 0; i < 4; ++i)
                op[(size_t)(q * 4 + i) * HWP] = acc[i] + bl[i];
        }
    }
}

extern "C" void kernel_launch(void* const* d_in, const int* in_sizes, int n_in,
                              void* d_out, int out_size, void* d_ws, size_t ws_size,
                              hipStream_t stream) {
    const float* x = (const float*)d_in[0];
    const float* w = (const float*)d_in[1];
    const float* b = (const float*)d_in[2];
    float* out = (float*)d_out;
    dim3 grid(HH / TH, WW / TW);   // y fastest -> vertical neighbors co-XCD
    conv3x3_wide<<<grid, dim3(256), 0, stream>>>(x, w, b, out);
}